// Round 1
// baseline (1292.681 us; speedup 1.0000x reference)
//
#include <hip/hip_runtime.h>
#include <math.h>

#define GX 128
#define GY 128
#define GZ 16
#define CELLS (GX*GY*GZ)   // 262144
#define NB 2               // batch
#define NV 100000          // voxels per batch
#define NM (NB*NV)         // 200000 rows
#define NN 8192            // queries per batch
#define NK 8               // keypoints per query
#define NC 64              // channels
#define EPSV 1e-5f
#define TM 128             // conv row tile

// ---------------- init: grid = -1, stats = 0 ----------------
__global__ void k_init(int* __restrict__ grid, float* __restrict__ stats) {
    int i = blockIdx.x * 256 + threadIdx.x;
    if (i < NB * CELLS) grid[i] = -1;
    else if (i < NB * CELLS + 512) stats[i - NB * CELLS] = 0.f;
}

// ---------------- scatter voxel rows into grid ----------------
__global__ void k_scatter(const int* __restrict__ coords, int* __restrict__ grid) {
    int gid = blockIdx.x * 256 + threadIdx.x;
    if (gid >= NM) return;
    int b = (gid >= NV) ? 1 : 0;
    int x = coords[gid * 3 + 0];
    int y = coords[gid * 3 + 1];
    int z = coords[gid * 3 + 2];
    grid[((b * GX + x) * GY + y) * GZ + z] = gid;
}

// ---------------- submanifold conv 3x3x3, C=64 -> 64 ----------------
// block: 256 threads, tile TM=128 rows. Each thread: 8 rows x 4 couts.
__global__ __launch_bounds__(256, 2) void k_conv(
    const float* __restrict__ feats, const int* __restrict__ coords,
    const int* __restrict__ grid, const float* __restrict__ W,
    float* __restrict__ out, float* __restrict__ gsum, float* __restrict__ gsq)
{
    __shared__ float s_nf[TM * 68];        // 34816 B (also reused: coords, reduction)
    __shared__ float s_w[64 * 64];         // 16384 B
    __shared__ int   s_nidx[27 * TM];      // 13824 B   -> total 65024 B

    int tid = threadIdx.x;
    int m0 = blockIdx.x * TM;

    // stage coords for this tile into (reused) s_nf region
    int* s_cx = (int*)s_nf;
    int* s_cy = s_cx + TM;
    int* s_cz = s_cy + TM;
    if (tid < TM) {
        int m = m0 + tid;
        if (m < NM) {
            s_cx[tid] = coords[m * 3 + 0];
            s_cy[tid] = coords[m * 3 + 1];
            s_cz[tid] = coords[m * 3 + 2];
        } else {
            s_cx[tid] = -1000; s_cy[tid] = -1000; s_cz[tid] = -1000;
        }
    }
    __syncthreads();

    // precompute all 27*TM neighbor indices
    for (int e = tid; e < 27 * TM; e += 256) {
        int k = e >> 7;          // TM = 128
        int r = e & (TM - 1);
        int dx = k / 9 - 1, dy = (k / 3) % 3 - 1, dz = k % 3 - 1;
        int nx = s_cx[r] + dx, ny = s_cy[r] + dy, nz = s_cz[r] + dz;
        int ni = -1;
        if (nx >= 0 && nx < GX && ny >= 0 && ny < GY && nz >= 0 && nz < GZ) {
            int b = ((m0 + r) >= NV) ? 1 : 0;
            ni = grid[((b * GX + nx) * GY + ny) * GZ + nz];
        }
        s_nidx[k * TM + r] = ni;
    }
    __syncthreads();

    float acc[8][4];
    #pragma unroll
    for (int i = 0; i < 8; ++i)
        #pragma unroll
        for (int j = 0; j < 4; ++j) acc[i][j] = 0.f;

    int rg = tid & 15;   // row group: rows rg + 16*i
    int cg = tid >> 4;   // col group: couts 4*cg + j

    for (int k = 0; k < 27; ++k) {
        // gather neighbor features (2 threads per row, 32 floats each)
        {
            int r = tid >> 1, p = tid & 1;
            int ni = s_nidx[k * TM + r];
            float4 v0, v1, v2, v3;
            if (ni >= 0) {
                const float4* src = (const float4*)(feats + (long)ni * 64 + p * 32);
                v0 = src[0]; v1 = src[1]; v2 = src[2]; v3 = src[3];
            } else {
                v0 = make_float4(0.f, 0.f, 0.f, 0.f); v1 = v0; v2 = v0; v3 = v0;
            }
            float4* dst = (float4*)(s_nf + r * 68 + p * 32);
            dst[0] = v0; dst[1] = v1; dst[2] = v2; dst[3] = v3;

            const float4* wsrc = (const float4*)(W + k * 4096);
            float4* wdst = (float4*)s_w;
            wdst[tid]        = wsrc[tid];
            wdst[tid + 256]  = wsrc[tid + 256];
            wdst[tid + 512]  = wsrc[tid + 512];
            wdst[tid + 768]  = wsrc[tid + 768];
        }
        __syncthreads();

        // 128x64x64 GEMM tile
        #pragma unroll 2
        for (int c4 = 0; c4 < 16; ++c4) {
            float aa[8][4];
            #pragma unroll
            for (int i = 0; i < 8; ++i) {
                float4 t = *(const float4*)(s_nf + (rg + 16 * i) * 68 + 4 * c4);
                aa[i][0] = t.x; aa[i][1] = t.y; aa[i][2] = t.z; aa[i][3] = t.w;
            }
            float bb[4][4];
            #pragma unroll
            for (int cc = 0; cc < 4; ++cc) {
                float4 t = *(const float4*)(s_w + (4 * c4 + cc) * 64 + 4 * cg);
                bb[cc][0] = t.x; bb[cc][1] = t.y; bb[cc][2] = t.z; bb[cc][3] = t.w;
            }
            #pragma unroll
            for (int i = 0; i < 8; ++i)
                #pragma unroll
                for (int j = 0; j < 4; ++j) {
                    float s = acc[i][j];
                    s += aa[i][0] * bb[0][j];
                    s += aa[i][1] * bb[1][j];
                    s += aa[i][2] * bb[2][j];
                    s += aa[i][3] * bb[3][j];
                    acc[i][j] = s;
                }
        }
        __syncthreads();
    }

    // store outputs
    #pragma unroll
    for (int i = 0; i < 8; ++i) {
        int m = m0 + rg + 16 * i;
        if (m < NM) {
            float4 v = make_float4(acc[i][0], acc[i][1], acc[i][2], acc[i][3]);
            *(float4*)(out + (long)m * 64 + 4 * cg) = v;
        }
    }

    // BN stats: per-thread channel partials (padded rows contribute exact 0)
    float ps[4] = {0.f, 0.f, 0.f, 0.f}, pq[4] = {0.f, 0.f, 0.f, 0.f};
    #pragma unroll
    for (int i = 0; i < 8; ++i)
        #pragma unroll
        for (int j = 0; j < 4; ++j) {
            ps[j] += acc[i][j];
            pq[j] += acc[i][j] * acc[i][j];
        }
    float* red = s_nf;  // reuse (safe: barrier at end of k-loop)
    #pragma unroll
    for (int j = 0; j < 4; ++j) {
        int c = 4 * cg + j;
        red[c * 16 + rg]        = ps[j];
        red[1024 + c * 16 + rg] = pq[j];
    }
    __syncthreads();
    if (tid < 64) {
        float ts = 0.f, tq = 0.f;
        #pragma unroll
        for (int r = 0; r < 16; ++r) {
            ts += red[tid * 16 + r];
            tq += red[1024 + tid * 16 + r];
        }
        atomicAdd(gsum + tid, ts);
        atomicAdd(gsq + tid, tq);
    }
}

// ---------------- BN coefficients ----------------
__global__ void k_bncoef(const float* __restrict__ gsum, const float* __restrict__ gsq,
                         const float* __restrict__ gamma, const float* __restrict__ beta,
                         float* __restrict__ coef) {
    int c = threadIdx.x;
    if (c >= 64) return;
    float mu = gsum[c] / (float)NM;
    float var = gsq[c] / (float)NM - mu * mu;
    float scale = gamma[c] / sqrtf(var + EPSV);
    coef[c] = scale;
    coef[64 + c] = beta[c] - mu * scale;
}

// ---------------- BN apply + ReLU ----------------
__global__ void k_bnapply(const float* __restrict__ in, const float* __restrict__ coef,
                          float* __restrict__ out) {
    int i = blockIdx.x * 256 + threadIdx.x;   // over NM*16 float4s
    if (i >= NM * 16) return;
    int c4 = (i & 15) * 4;
    float4 v = ((const float4*)in)[i];
    float4 sc = *(const float4*)(coef + c4);
    float4 sh = *(const float4*)(coef + 64 + c4);
    v.x = fmaxf(v.x * sc.x + sh.x, 0.f);
    v.y = fmaxf(v.y * sc.y + sh.y, 0.f);
    v.z = fmaxf(v.z * sc.z + sh.z, 0.f);
    v.w = fmaxf(v.w * sc.w + sh.w, 0.f);
    ((float4*)out)[i] = v;
}

// ---------------- keypoint sampling + fuse + projection ----------------
// 1 wave per query row; 4 waves per block.
__global__ __launch_bounds__(256) void k_sample(
    const float* __restrict__ kp, const float* __restrict__ query,
    const float* __restrict__ feats2, const int* __restrict__ grid,
    const float* __restrict__ projW, const float* __restrict__ projB,
    float* __restrict__ out_fused, float* __restrict__ out_vi)
{
    __shared__ float s_pw[64 * 65];
    __shared__ float s_mean[4][64];
    __shared__ int   s_idx[4][8];

    int tid = threadIdx.x;
    for (int e = tid; e < 4096; e += 256) {
        int co = e >> 6, c = e & 63;
        s_pw[co * 65 + c] = projW[e];
    }

    int w = tid >> 6, lane = tid & 63;
    int row = blockIdx.x * 4 + w;   // < 16384
    int b = row >> 13;              // NN = 8192
    __syncthreads();

    if (lane < 8) {
        int kk = lane;
        const float* kpp = kp + ((long)row * 8 + kk) * 3;
        int qx = min(max((int)(kpp[0] * 2.0f), 0), GX - 1);
        int qy = min(max((int)(kpp[1] * 2.0f), 0), GY - 1);
        int qz = min(max((int)(kpp[2] * 2.0f), 0), GZ - 1);
        s_idx[w][kk] = grid[((b * GX + qx) * GY + qy) * GZ + qz];
        float4 vi = make_float4((float)b, (float)qx, (float)qy, (float)qz);
        *(float4*)(out_vi + ((long)row * 8 + kk) * 4) = vi;
    }
    __syncthreads();

    float acc = 0.f;
    #pragma unroll
    for (int kk = 0; kk < 8; ++kk) {
        int gi = s_idx[w][kk];
        gi = gi < 0 ? 0 : gi;
        acc += feats2[(long)gi * 64 + lane];
    }
    float mean = acc * 0.125f + query[(long)row * 64 + lane];
    s_mean[w][lane] = mean;
    __syncthreads();

    float f = projB[lane];
    const float* pwr = s_pw + lane * 65;
    const float* mv = s_mean[w];
    #pragma unroll 8
    for (int c = 0; c < 64; ++c) f += mv[c] * pwr[c];
    out_fused[(long)row * 64 + lane] = f;
}

// ---------------- launch ----------------
extern "C" void kernel_launch(void* const* d_in, const int* in_sizes, int n_in,
                              void* d_out, int out_size, void* d_ws, size_t ws_size,
                              hipStream_t stream) {
    const float* keypoints = (const float*)d_in[0];
    const float* query     = (const float*)d_in[1];
    const float* vfeat     = (const float*)d_in[2];
    const int*   vcoords   = (const int*)d_in[3];
    const float* W1        = (const float*)d_in[4];
    const float* g1        = (const float*)d_in[5];
    const float* b1        = (const float*)d_in[6];
    const float* W2        = (const float*)d_in[7];
    const float* g2        = (const float*)d_in[8];
    const float* b2        = (const float*)d_in[9];
    const float* pW        = (const float*)d_in[10];
    const float* pb        = (const float*)d_in[11];

    char* ws = (char*)d_ws;
    int*   grid  = (int*)ws;                                   // 2,097,152 B
    float* stats = (float*)(ws + 2097152);                     // 512 floats used
    float* buf0  = (float*)(ws + 2101248);                     // 51,200,000 B
    float* buf1  = (float*)(ws + 2101248 + 51200000);          // 51,200,000 B

    float* sum1 = stats,        *sq1 = stats + 64,  *coef1 = stats + 128;
    float* sum2 = stats + 256,  *sq2 = stats + 320, *coef2 = stats + 384;

    int initN = NB * CELLS + 512;
    k_init<<<(initN + 255) / 256, 256, 0, stream>>>(grid, stats);
    k_scatter<<<(NM + 255) / 256, 256, 0, stream>>>(vcoords, grid);

    k_conv<<<(NM + TM - 1) / TM, 256, 0, stream>>>(vfeat, vcoords, grid, W1, buf0, sum1, sq1);
    k_bncoef<<<1, 64, 0, stream>>>(sum1, sq1, g1, b1, coef1);
    k_bnapply<<<(NM * 16 + 255) / 256, 256, 0, stream>>>(buf0, coef1, buf1);

    k_conv<<<(NM + TM - 1) / TM, 256, 0, stream>>>(buf1, vcoords, grid, W2, buf0, sum2, sq2);
    k_bncoef<<<1, 64, 0, stream>>>(sum2, sq2, g2, b2, coef2);
    k_bnapply<<<(NM * 16 + 255) / 256, 256, 0, stream>>>(buf0, coef2, buf1);

    float* out_fused = (float*)d_out;
    float* out_vi = out_fused + (long)NB * NN * NC;   // 1,048,576
    k_sample<<<(NB * NN) / 4, 256, 0, stream>>>(keypoints, query, buf1, grid, pW, pb,
                                                out_fused, out_vi);
}

// Round 2
// 629.124 us; speedup vs baseline: 2.0547x; 2.0547x over previous
//
#include <hip/hip_runtime.h>
#include <hip/hip_bf16.h>
#include <math.h>

#define GX 128
#define GY 128
#define GZ 16
#define CELLS (GX*GY*GZ)   // 262144
#define NB 2
#define NV 100000
#define NM (NB*NV)         // 200000
#define NN 8192
#define NK 8
#define NC 64
#define EPSV 1e-5f
#define TM 128             // conv row tile
#define LDA 72             // padded LDS row stride in bf16 elems (144 B -> 2-way max)

typedef __attribute__((ext_vector_type(8))) short short8;    // 8 bf16
typedef __attribute__((ext_vector_type(4))) float floatx4;   // MFMA C/D

__device__ __forceinline__ float bf2f(unsigned short u) {
    unsigned int x = ((unsigned int)u) << 16;
    return __builtin_bit_cast(float, x);
}
__device__ __forceinline__ unsigned short f2bf(float f) {
    unsigned int u = __builtin_bit_cast(unsigned int, f);
    return (unsigned short)((u + 0x7fffu + ((u >> 16) & 1u)) >> 16);
}

// ---------------- init: grid = -1, stats = 0 ----------------
__global__ void k_init(int* __restrict__ grid, float* __restrict__ stats) {
    int i = blockIdx.x * 256 + threadIdx.x;
    if (i < NB * CELLS) grid[i] = -1;
    else if (i < NB * CELLS + 512) stats[i - NB * CELLS] = 0.f;
}

// ---------------- scatter voxel rows into grid ----------------
__global__ void k_scatter(const int* __restrict__ coords, int* __restrict__ grid) {
    int gid = blockIdx.x * 256 + threadIdx.x;
    if (gid >= NM) return;
    int b = (gid >= NV) ? 1 : 0;
    int x = coords[gid * 3 + 0];
    int y = coords[gid * 3 + 1];
    int z = coords[gid * 3 + 2];
    grid[((b * GX + x) * GY + y) * GZ + z] = gid;
}

// ---------------- weight prep: transpose + bf16 ----------------
// Wt[k][cout][cin] = W[k][cin][cout]  (B-fragment reads become contiguous in cin)
__global__ void k_wprep(const float* __restrict__ W1, const float* __restrict__ W2,
                        unsigned short* __restrict__ Wt1, unsigned short* __restrict__ Wt2) {
    int e = blockIdx.x * 256 + threadIdx.x;
    if (e >= 27 * 64 * 64) return;
    int k = e >> 12, r = e & 4095, co = r >> 6, ci = r & 63;
    Wt1[e] = f2bf(W1[(k << 12) + ci * 64 + co]);
    Wt2[e] = f2bf(W2[(k << 12) + ci * 64 + co]);
}

// ---------------- fp32 -> bf16 feature convert ----------------
__global__ void k_tobf16(const float* __restrict__ in, unsigned short* __restrict__ out, int n4) {
    int i = blockIdx.x * 256 + threadIdx.x;
    if (i >= n4) return;
    float4 v = ((const float4*)in)[i];
    ushort4 o;
    o.x = f2bf(v.x); o.y = f2bf(v.y); o.z = f2bf(v.z); o.w = f2bf(v.w);
    ((ushort4*)out)[i] = o;
}

// ---------------- submanifold conv 3x3x3, C=64->64, bf16 MFMA ----------------
// block: 256 threads (4 waves). Tile: 128 rows x 64 couts.
// Wave w: row-tiles {2w,2w+1} (rows 32w..32w+31), all 4 col-tiles.
// K-loop: 27 offsets x (Cin=64 = 2 MFMA ksteps of 32).
__global__ __launch_bounds__(256, 3) void k_conv(
    const unsigned short* __restrict__ feats, const int* __restrict__ coords,
    const int* __restrict__ grid, const unsigned short* __restrict__ Wt,
    unsigned short* __restrict__ out, float* __restrict__ gsum, float* __restrict__ gsq)
{
    __shared__ unsigned short s_a[2][TM * LDA];   // 36864 B (double-buffered A tile)
    __shared__ int s_nidx[27 * TM];               // 13824 B (reused for BN reduction)

    int tid = threadIdx.x;
    int m0 = blockIdx.x * TM;

    // stage coords into s_a[0] (overwritten later by A staging)
    int* s_cx = (int*)&s_a[0][0];
    int* s_cy = s_cx + TM;
    int* s_cz = s_cy + TM;
    if (tid < TM) {
        int m = m0 + tid;
        if (m < NM) {
            s_cx[tid] = coords[m * 3 + 0];
            s_cy[tid] = coords[m * 3 + 1];
            s_cz[tid] = coords[m * 3 + 2];
        } else {
            s_cx[tid] = -1000; s_cy[tid] = -1000; s_cz[tid] = -1000;
        }
    }
    __syncthreads();

    // precompute 27*TM neighbor row indices
    for (int e = tid; e < 27 * TM; e += 256) {
        int k = e >> 7;
        int r = e & (TM - 1);
        int dx = k / 9 - 1, dy = (k / 3) % 3 - 1, dz = k % 3 - 1;
        int nx = s_cx[r] + dx, ny = s_cy[r] + dy, nz = s_cz[r] + dz;
        int ni = -1;
        if (nx >= 0 && nx < GX && ny >= 0 && ny < GY && nz >= 0 && nz < GZ) {
            int b = ((m0 + r) >= NV) ? 1 : 0;
            ni = grid[((b * GX + nx) * GY + ny) * GZ + nz];
        }
        s_nidx[k * TM + r] = ni;
    }
    __syncthreads();

    int r_st = tid >> 1, p_st = tid & 1;  // staging: row, 64B-half (row = 128 B bf16)

    // prologue: stage k=0 into buf 0
    {
        int ni = s_nidx[r_st];
        uint4 v0 = {0,0,0,0}, v1 = v0, v2 = v0, v3 = v0;
        if (ni >= 0) {
            const uint4* src = (const uint4*)(feats + (size_t)ni * 64 + p_st * 32);
            v0 = src[0]; v1 = src[1]; v2 = src[2]; v3 = src[3];
        }
        uint4* dst = (uint4*)&s_a[0][r_st * LDA + p_st * 32];
        dst[0] = v0; dst[1] = v1; dst[2] = v2; dst[3] = v3;
    }
    __syncthreads();

    int w = tid >> 6, lane = tid & 63;
    int quad = lane >> 4, n16 = lane & 15;

    floatx4 acc[2][4];
    #pragma unroll
    for (int rt = 0; rt < 2; ++rt)
        #pragma unroll
        for (int ct = 0; ct < 4; ++ct)
            acc[rt][ct] = (floatx4){0.f, 0.f, 0.f, 0.f};

    for (int k = 0; k < 27; ++k) {
        int cur = k & 1;
        // prefetch next A tile into regs (consumed after MFMAs)
        uint4 v0 = {0,0,0,0}, v1 = v0, v2 = v0, v3 = v0;
        bool pf = (k < 26);
        if (pf) {
            int ni = s_nidx[(k + 1) * TM + r_st];
            if (ni >= 0) {
                const uint4* src = (const uint4*)(feats + (size_t)ni * 64 + p_st * 32);
                v0 = src[0]; v1 = src[1]; v2 = src[2]; v3 = src[3];
            }
        }
        // B fragments from global (L1-hot, 8 KB per offset)
        const unsigned short* wb = Wt + (k << 12);
        short8 bfr[4][2];
        #pragma unroll
        for (int ct = 0; ct < 4; ++ct)
            #pragma unroll
            for (int ks = 0; ks < 2; ++ks)
                bfr[ct][ks] = *(const short8*)(wb + (ct * 16 + n16) * 64 + ks * 32 + quad * 8);
        // A fragments from LDS
        short8 afr[2][2];
        #pragma unroll
        for (int rt = 0; rt < 2; ++rt)
            #pragma unroll
            for (int ks = 0; ks < 2; ++ks)
                afr[rt][ks] = *(const short8*)&s_a[cur][((2 * w + rt) * 16 + n16) * LDA + ks * 32 + quad * 8];
        #pragma unroll
        for (int ks = 0; ks < 2; ++ks)
            #pragma unroll
            for (int rt = 0; rt < 2; ++rt)
                #pragma unroll
                for (int ct = 0; ct < 4; ++ct)
                    acc[rt][ct] = __builtin_amdgcn_mfma_f32_16x16x32_bf16(
                        afr[rt][ks], bfr[ct][ks], acc[rt][ct], 0, 0, 0);
        if (pf) {
            uint4* dst = (uint4*)&s_a[cur ^ 1][r_st * LDA + p_st * 32];
            dst[0] = v0; dst[1] = v1; dst[2] = v2; dst[3] = v3;
        }
        __syncthreads();
    }

    // store bf16 conv output.  C/D layout: col = lane&15, row = quad*4 + reg
    #pragma unroll
    for (int rt = 0; rt < 2; ++rt) {
        int rbase = m0 + (2 * w + rt) * 16 + quad * 4;
        #pragma unroll
        for (int rg = 0; rg < 4; ++rg) {
            int m = rbase + rg;
            if (m < NM) {
                #pragma unroll
                for (int ct = 0; ct < 4; ++ct)
                    out[(size_t)m * 64 + ct * 16 + n16] = f2bf(acc[rt][ct][rg]);
            }
        }
    }

    // BN stats from exact fp32 accumulators (pad rows are exact 0)
    float ps[4], pq[4];
    #pragma unroll
    for (int ct = 0; ct < 4; ++ct) { ps[ct] = 0.f; pq[ct] = 0.f; }
    #pragma unroll
    for (int rt = 0; rt < 2; ++rt)
        #pragma unroll
        for (int ct = 0; ct < 4; ++ct)
            #pragma unroll
            for (int rg = 0; rg < 4; ++rg) {
                float v = acc[rt][ct][rg];
                ps[ct] += v;
                pq[ct] += v * v;
            }
    // reduce across quads (lane bits 4,5)
    #pragma unroll
    for (int ct = 0; ct < 4; ++ct) {
        ps[ct] += __shfl_xor(ps[ct], 16);
        ps[ct] += __shfl_xor(ps[ct], 32);
        pq[ct] += __shfl_xor(pq[ct], 16);
        pq[ct] += __shfl_xor(pq[ct], 32);
    }
    float* red = (float*)s_nidx;  // safe: s_nidx dead after final barrier of k-loop
    if (lane < 16) {
        #pragma unroll
        for (int ct = 0; ct < 4; ++ct) {
            red[w * 64 + ct * 16 + n16]       = ps[ct];
            red[256 + w * 64 + ct * 16 + n16] = pq[ct];
        }
    }
    __syncthreads();
    if (tid < 64) {
        float ts = 0.f, tq = 0.f;
        #pragma unroll
        for (int ww = 0; ww < 4; ++ww) {
            ts += red[ww * 64 + tid];
            tq += red[256 + ww * 64 + tid];
        }
        atomicAdd(gsum + tid, ts);
        atomicAdd(gsq + tid, tq);
    }
}

// ---------------- BN coefficients ----------------
__global__ void k_bncoef(const float* __restrict__ gsum, const float* __restrict__ gsq,
                         const float* __restrict__ gamma, const float* __restrict__ beta,
                         float* __restrict__ coef) {
    int c = threadIdx.x;
    if (c >= 64) return;
    float mu = gsum[c] / (float)NM;
    float var = gsq[c] / (float)NM - mu * mu;
    float scale = gamma[c] / sqrtf(var + EPSV);
    coef[c] = scale;
    coef[64 + c] = beta[c] - mu * scale;
}

// ---------------- BN apply + ReLU (bf16 -> bf16) ----------------
__global__ void k_bnapply(const unsigned short* __restrict__ in, const float* __restrict__ coef,
                          unsigned short* __restrict__ out) {
    int i = blockIdx.x * 256 + threadIdx.x;  // over NM*8 groups of 8 bf16
    if (i >= NM * 8) return;
    int c8 = (i & 7) * 8;
    uint4 v = ((const uint4*)in)[i];
    unsigned int vv[4] = {v.x, v.y, v.z, v.w};
    unsigned int oo[4];
    #pragma unroll
    for (int j = 0; j < 4; ++j) {
        int c = c8 + j * 2;
        float lo = bf2f((unsigned short)(vv[j] & 0xffffu));
        float hi = bf2f((unsigned short)(vv[j] >> 16));
        lo = fmaxf(lo * coef[c]     + coef[64 + c],     0.f);
        hi = fmaxf(hi * coef[c + 1] + coef[64 + c + 1], 0.f);
        oo[j] = (unsigned int)f2bf(lo) | ((unsigned int)f2bf(hi) << 16);
    }
    uint4 o = {oo[0], oo[1], oo[2], oo[3]};
    ((uint4*)out)[i] = o;
}

// ---------------- keypoint sampling + fuse + projection ----------------
__global__ __launch_bounds__(256) void k_sample(
    const float* __restrict__ kp, const float* __restrict__ query,
    const unsigned short* __restrict__ feats2, const int* __restrict__ grid,
    const float* __restrict__ projW, const float* __restrict__ projB,
    float* __restrict__ out_fused, float* __restrict__ out_vi)
{
    __shared__ float s_pw[64 * 65];
    __shared__ float s_mean[4][64];
    __shared__ int   s_idx[4][8];

    int tid = threadIdx.x;
    for (int e = tid; e < 4096; e += 256) {
        int co = e >> 6, c = e & 63;
        s_pw[co * 65 + c] = projW[e];
    }

    int w = tid >> 6, lane = tid & 63;
    int row = blockIdx.x * 4 + w;   // < 16384
    int b = row >> 13;              // NN = 8192
    __syncthreads();

    if (lane < 8) {
        int kk = lane;
        const float* kpp = kp + ((size_t)row * 8 + kk) * 3;
        int qx = min(max((int)(kpp[0] * 2.0f), 0), GX - 1);
        int qy = min(max((int)(kpp[1] * 2.0f), 0), GY - 1);
        int qz = min(max((int)(kpp[2] * 2.0f), 0), GZ - 1);
        s_idx[w][kk] = grid[((b * GX + qx) * GY + qy) * GZ + qz];
        float4 vi = make_float4((float)b, (float)qx, (float)qy, (float)qz);
        *(float4*)(out_vi + ((size_t)row * 8 + kk) * 4) = vi;
    }
    __syncthreads();

    float acc = 0.f;
    #pragma unroll
    for (int kk = 0; kk < 8; ++kk) {
        int gi = s_idx[w][kk];
        gi = gi < 0 ? 0 : gi;
        acc += bf2f(feats2[(size_t)gi * 64 + lane]);
    }
    float mean = acc * 0.125f + query[(size_t)row * 64 + lane];
    s_mean[w][lane] = mean;
    __syncthreads();

    float f = projB[lane];
    const float* pwr = s_pw + lane * 65;
    const float* mv = s_mean[w];
    #pragma unroll 8
    for (int c = 0; c < 64; ++c) f += mv[c] * pwr[c];
    out_fused[(size_t)row * 64 + lane] = f;
}

// ---------------- launch ----------------
extern "C" void kernel_launch(void* const* d_in, const int* in_sizes, int n_in,
                              void* d_out, int out_size, void* d_ws, size_t ws_size,
                              hipStream_t stream) {
    const float* keypoints = (const float*)d_in[0];
    const float* query     = (const float*)d_in[1];
    const float* vfeat     = (const float*)d_in[2];
    const int*   vcoords   = (const int*)d_in[3];
    const float* W1        = (const float*)d_in[4];
    const float* g1        = (const float*)d_in[5];
    const float* b1        = (const float*)d_in[6];
    const float* W2        = (const float*)d_in[7];
    const float* g2        = (const float*)d_in[8];
    const float* b2        = (const float*)d_in[9];
    const float* pW        = (const float*)d_in[10];
    const float* pb        = (const float*)d_in[11];

    char* ws = (char*)d_ws;
    int*            grid   = (int*)ws;                          // 2,097,152 B
    float*          stats  = (float*)(ws + 2097152);            // 2048 B
    unsigned short* Wt1    = (unsigned short*)(ws + 2099200);   // 221,184 B
    unsigned short* Wt2    = (unsigned short*)(ws + 2320384);   // 221,184 B
    unsigned short* featA  = (unsigned short*)(ws + 2541568);   // 25,600,000 B
    unsigned short* featB  = (unsigned short*)(ws + 28141568);  // 25,600,000 B
    unsigned short* convo  = (unsigned short*)(ws + 53741568);  // 25,600,000 B

    float* sum1 = stats,       *sq1 = stats + 64,  *coef1 = stats + 128;
    float* sum2 = stats + 256, *sq2 = stats + 320, *coef2 = stats + 384;

    int initN = NB * CELLS + 512;
    k_init<<<(initN + 255) / 256, 256, 0, stream>>>(grid, stats);
    k_scatter<<<(NM + 255) / 256, 256, 0, stream>>>(vcoords, grid);
    k_wprep<<<(27 * 64 * 64 + 255) / 256, 256, 0, stream>>>(W1, W2, Wt1, Wt2);
    k_tobf16<<<(NM * 16 + 255) / 256, 256, 0, stream>>>(vfeat, featA, NM * 16);

    k_conv<<<(NM + TM - 1) / TM, 256, 0, stream>>>(featA, vcoords, grid, Wt1, convo, sum1, sq1);
    k_bncoef<<<1, 64, 0, stream>>>(sum1, sq1, g1, b1, coef1);
    k_bnapply<<<(NM * 8 + 255) / 256, 256, 0, stream>>>(convo, coef1, featB);

    k_conv<<<(NM + TM - 1) / TM, 256, 0, stream>>>(featB, vcoords, grid, Wt2, convo, sum2, sq2);
    k_bncoef<<<1, 64, 0, stream>>>(sum2, sq2, g2, b2, coef2);
    k_bnapply<<<(NM * 8 + 255) / 256, 256, 0, stream>>>(convo, coef2, featA);

    float* out_fused = (float*)d_out;
    float* out_vi = out_fused + (size_t)NB * NN * NC;  // 1,048,576 floats
    k_sample<<<(NB * NN) / 4, 256, 0, stream>>>(keypoints, query, featA, grid, pW, pb,
                                                out_fused, out_vi);
}

// Round 3
// 566.100 us; speedup vs baseline: 2.2835x; 1.1113x over previous
//
#include <hip/hip_runtime.h>
#include <hip/hip_bf16.h>
#include <math.h>

#define GX 128
#define GY 128
#define GZ 16
#define CELLS (GX*GY*GZ)   // 262144
#define NB 2
#define NV 100000
#define NM (NB*NV)         // 200000
#define NN 8192
#define NK 8
#define NC 64
#define EPSV 1e-5f
#define TM 128             // conv row tile (32 rows per wave)
#define LDA 72             // padded LDS row stride (bf16 elems)

typedef __attribute__((ext_vector_type(8))) short short8;    // 8 bf16
typedef __attribute__((ext_vector_type(4))) float floatx4;   // MFMA C/D

__device__ __forceinline__ float bf2f(unsigned short u) {
    unsigned int x = ((unsigned int)u) << 16;
    return __builtin_bit_cast(float, x);
}
__device__ __forceinline__ unsigned short f2bf(float f) {
    unsigned int u = __builtin_bit_cast(unsigned int, f);
    return (unsigned short)((u + 0x7fffu + ((u >> 16) & 1u)) >> 16);
}

// ---------------- init: grid = -1, stats = 0 ----------------
__global__ void k_init(int* __restrict__ grid, float* __restrict__ stats) {
    int i = blockIdx.x * 256 + threadIdx.x;
    if (i < NB * CELLS) grid[i] = -1;
    else if (i < NB * CELLS + 512) stats[i - NB * CELLS] = 0.f;
}

// ---------------- scatter voxel rows into grid ----------------
__global__ void k_scatter(const int* __restrict__ coords, int* __restrict__ grid) {
    int gid = blockIdx.x * 256 + threadIdx.x;
    if (gid >= NM) return;
    int b = (gid >= NV) ? 1 : 0;
    int x = coords[gid * 3 + 0];
    int y = coords[gid * 3 + 1];
    int z = coords[gid * 3 + 2];
    grid[((b * GX + x) * GY + y) * GZ + z] = gid;
}

// ---------------- weight prep: transpose + bf16 ----------------
__global__ void k_wprep(const float* __restrict__ W1, const float* __restrict__ W2,
                        unsigned short* __restrict__ Wt1, unsigned short* __restrict__ Wt2) {
    int e = blockIdx.x * 256 + threadIdx.x;
    if (e >= 27 * 64 * 64) return;
    int k = e >> 12, r = e & 4095, co = r >> 6, ci = r & 63;
    Wt1[e] = f2bf(W1[(k << 12) + ci * 64 + co]);
    Wt2[e] = f2bf(W2[(k << 12) + ci * 64 + co]);
}

// ---------------- fp32 -> bf16 feature convert ----------------
__global__ void k_tobf16(const float* __restrict__ in, unsigned short* __restrict__ out, int n4) {
    int i = blockIdx.x * 256 + threadIdx.x;
    if (i >= n4) return;
    float4 v = ((const float4*)in)[i];
    ushort4 o;
    o.x = f2bf(v.x); o.y = f2bf(v.y); o.z = f2bf(v.z); o.w = f2bf(v.w);
    ((ushort4*)out)[i] = o;
}

// ---------------- submanifold conv 3x3x3, C=64->64, bf16 MFMA ----------------
// Barrier-free K-loop: each wave owns rows 32w..32w+31 with a private
// double-buffered LDS A region.  Register prefetch: A depth-3, B depth-2,
// issue order B(k+1), A(k+3), [mfma k], commit A(k+1) -> vmcnt FIFO keeps
// the A gather loads in flight across ~2.5 iterations.
__global__ __launch_bounds__(256, 2) void k_conv(
    const unsigned short* __restrict__ feats, const int* __restrict__ coords,
    const int* __restrict__ grid, const unsigned short* __restrict__ Wt,
    unsigned short* __restrict__ out, float* __restrict__ gsum, float* __restrict__ gsq)
{
    __shared__ unsigned short s_a[4][2][32 * LDA];  // 36864 B: per-wave double buffer
    __shared__ int s_nidx[27 * TM];                 // 13824 B; reused for BN reduction

    int tid = threadIdx.x;
    int m0 = blockIdx.x * TM;

    // stage coords (into wave-0 A region, dead until after barrier 2)
    int* s_cx = (int*)&s_a[0][0][0];
    int* s_cy = s_cx + TM;
    int* s_cz = s_cy + TM;
    if (tid < TM) {
        int m = m0 + tid;
        if (m < NM) {
            s_cx[tid] = coords[m * 3 + 0];
            s_cy[tid] = coords[m * 3 + 1];
            s_cz[tid] = coords[m * 3 + 2];
        } else {
            s_cx[tid] = -1000; s_cy[tid] = -1000; s_cz[tid] = -1000;
        }
    }
    __syncthreads();

    for (int e = tid; e < 27 * TM; e += 256) {
        int k = e >> 7;
        int r = e & (TM - 1);
        int dx = k / 9 - 1, dy = (k / 3) % 3 - 1, dz = k % 3 - 1;
        int nx = s_cx[r] + dx, ny = s_cy[r] + dy, nz = s_cz[r] + dz;
        int ni = -1;
        if (nx >= 0 && nx < GX && ny >= 0 && ny < GY && nz >= 0 && nz < GZ) {
            int b = ((m0 + r) >= NV) ? 1 : 0;
            ni = grid[((b * GX + nx) * GY + ny) * GZ + nz];
        }
        s_nidx[k * TM + r] = ni;
    }
    __syncthreads();

    int w = tid >> 6, lane = tid & 63;
    int quad = lane >> 4, n16 = lane & 15;
    int lr = lane >> 1, h = lane & 1;   // staged local row, 64B-half
    int grow = w * 32 + lr;             // tile row this lane stages

    unsigned short* st0 = &s_a[w][0][lr * LDA + h * 32];
    unsigned short* st1 = &s_a[w][1][lr * LDA + h * 32];

    uint4 p[3][4];        // A prefetch, depth 3
    short8 bfr[2][8];     // B prefetch, depth 2: [slot][ct*2+ks]

    auto issueA = [&](int k, uint4* pv) {
        int ni = s_nidx[k * TM + grow];
        uint4 z = {0u, 0u, 0u, 0u};
        pv[0] = z; pv[1] = z; pv[2] = z; pv[3] = z;
        if (ni >= 0) {
            const uint4* s = (const uint4*)(feats + (size_t)ni * 64 + h * 32);
            pv[0] = s[0]; pv[1] = s[1]; pv[2] = s[2]; pv[3] = s[3];
        }
    };
    auto commitA = [&](int k, uint4* pv) {
        uint4* d = (uint4*)((k & 1) ? st1 : st0);
        d[0] = pv[0]; d[1] = pv[1]; d[2] = pv[2]; d[3] = pv[3];
    };
    auto issueB = [&](int k, short8* bf) {
        const unsigned short* wb = Wt + (k << 12) + n16 * 64 + quad * 8;
        #pragma unroll
        for (int ct = 0; ct < 4; ++ct)
            #pragma unroll
            for (int ks = 0; ks < 2; ++ks)
                bf[ct * 2 + ks] = *(const short8*)(wb + ct * 1024 + ks * 32);
    };

    floatx4 acc[2][4];
    #pragma unroll
    for (int rt = 0; rt < 2; ++rt)
        #pragma unroll
        for (int ct = 0; ct < 4; ++ct)
            acc[rt][ct] = (floatx4){0.f, 0.f, 0.f, 0.f};

    // prologue (B(0) oldest in queue so waiting it never drains A prefetch)
    issueB(0, bfr[0]);
    issueA(0, p[0]);
    issueA(1, p[1]);
    issueA(2, p[2]);
    commitA(0, p[0]);

    #pragma unroll
    for (int k = 0; k < 27; ++k) {
        if (k < 26) issueB(k + 1, bfr[(k + 1) & 1]);
        if (k + 3 <= 26) issueA(k + 3, p[k % 3]);

        const unsigned short* ab = &s_a[w][k & 1][0];
        short8 afr[2][2];
        #pragma unroll
        for (int rt = 0; rt < 2; ++rt)
            #pragma unroll
            for (int ks = 0; ks < 2; ++ks)
                afr[rt][ks] = *(const short8*)(ab + (rt * 16 + n16) * LDA + ks * 32 + quad * 8);

        const short8* bc = bfr[k & 1];
        #pragma unroll
        for (int ks = 0; ks < 2; ++ks)
            #pragma unroll
            for (int rt = 0; rt < 2; ++rt)
                #pragma unroll
                for (int ct = 0; ct < 4; ++ct)
                    acc[rt][ct] = __builtin_amdgcn_mfma_f32_16x16x32_bf16(
                        afr[rt][ks], bc[ct * 2 + ks], acc[rt][ct], 0, 0, 0);

        if (k < 26) commitA(k + 1, p[(k + 1) % 3]);
    }

    // store bf16 conv output.  C/D layout: col = lane&15, row = quad*4 + reg
    #pragma unroll
    for (int rt = 0; rt < 2; ++rt) {
        int rbase = m0 + w * 32 + rt * 16 + quad * 4;
        #pragma unroll
        for (int rg = 0; rg < 4; ++rg) {
            int m = rbase + rg;
            if (m < NM) {
                #pragma unroll
                for (int ct = 0; ct < 4; ++ct)
                    out[(size_t)m * 64 + ct * 16 + n16] = f2bf(acc[rt][ct][rg]);
            }
        }
    }

    // BN stats from fp32 accumulators (pad rows are exact 0)
    float ps[4], pq[4];
    #pragma unroll
    for (int ct = 0; ct < 4; ++ct) { ps[ct] = 0.f; pq[ct] = 0.f; }
    #pragma unroll
    for (int rt = 0; rt < 2; ++rt)
        #pragma unroll
        for (int ct = 0; ct < 4; ++ct)
            #pragma unroll
            for (int rg = 0; rg < 4; ++rg) {
                float v = acc[rt][ct][rg];
                ps[ct] += v;
                pq[ct] += v * v;
            }
    #pragma unroll
    for (int ct = 0; ct < 4; ++ct) {
        ps[ct] += __shfl_xor(ps[ct], 16);
        ps[ct] += __shfl_xor(ps[ct], 32);
        pq[ct] += __shfl_xor(pq[ct], 16);
        pq[ct] += __shfl_xor(pq[ct], 32);
    }
    __syncthreads();              // all waves done with s_nidx before reuse
    float* red = (float*)s_nidx;
    if (lane < 16) {
        #pragma unroll
        for (int ct = 0; ct < 4; ++ct) {
            red[w * 64 + ct * 16 + n16]       = ps[ct];
            red[256 + w * 64 + ct * 16 + n16] = pq[ct];
        }
    }
    __syncthreads();
    if (tid < 64) {
        float ts = 0.f, tq = 0.f;
        #pragma unroll
        for (int ww = 0; ww < 4; ++ww) {
            ts += red[ww * 64 + tid];
            tq += red[256 + ww * 64 + tid];
        }
        atomicAdd(gsum + tid, ts);
        atomicAdd(gsq + tid, tq);
    }
}

// ---------------- BN coefficients ----------------
__global__ void k_bncoef(const float* __restrict__ gsum, const float* __restrict__ gsq,
                         const float* __restrict__ gamma, const float* __restrict__ beta,
                         float* __restrict__ coef) {
    int c = threadIdx.x;
    if (c >= 64) return;
    float mu = gsum[c] / (float)NM;
    float var = gsq[c] / (float)NM - mu * mu;
    float scale = gamma[c] / sqrtf(var + EPSV);
    coef[c] = scale;
    coef[64 + c] = beta[c] - mu * scale;
}

// ---------------- BN apply + ReLU (bf16 -> bf16) ----------------
__global__ void k_bnapply(const unsigned short* __restrict__ in, const float* __restrict__ coef,
                          unsigned short* __restrict__ out) {
    int i = blockIdx.x * 256 + threadIdx.x;  // over NM*8 groups of 8 bf16
    if (i >= NM * 8) return;
    int c8 = (i & 7) * 8;
    uint4 v = ((const uint4*)in)[i];
    unsigned int vv[4] = {v.x, v.y, v.z, v.w};
    unsigned int oo[4];
    #pragma unroll
    for (int j = 0; j < 4; ++j) {
        int c = c8 + j * 2;
        float lo = bf2f((unsigned short)(vv[j] & 0xffffu));
        float hi = bf2f((unsigned short)(vv[j] >> 16));
        lo = fmaxf(lo * coef[c]     + coef[64 + c],     0.f);
        hi = fmaxf(hi * coef[c + 1] + coef[64 + c + 1], 0.f);
        oo[j] = (unsigned int)f2bf(lo) | ((unsigned int)f2bf(hi) << 16);
    }
    uint4 o = {oo[0], oo[1], oo[2], oo[3]};
    ((uint4*)out)[i] = o;
}

// ---------------- keypoint sampling + fused BN2/ReLU + projection ----------------
__global__ __launch_bounds__(256) void k_sample(
    const float* __restrict__ kp, const float* __restrict__ query,
    const unsigned short* __restrict__ conv2, const float* __restrict__ coef2,
    const int* __restrict__ grid,
    const float* __restrict__ projW, const float* __restrict__ projB,
    float* __restrict__ out_fused, float* __restrict__ out_vi)
{
    __shared__ float s_pw[64 * 65];
    __shared__ float s_mean[4][64];
    __shared__ int   s_idx[4][8];

    int tid = threadIdx.x;
    for (int e = tid; e < 4096; e += 256) {
        int co = e >> 6, c = e & 63;
        s_pw[co * 65 + c] = projW[e];
    }

    int w = tid >> 6, lane = tid & 63;
    int row = blockIdx.x * 4 + w;   // < 16384
    int b = row >> 13;              // NN = 8192
    float sc = coef2[lane];
    float sh = coef2[64 + lane];
    __syncthreads();

    if (lane < 8) {
        int kk = lane;
        const float* kpp = kp + ((size_t)row * 8 + kk) * 3;
        int qx = min(max((int)(kpp[0] * 2.0f), 0), GX - 1);
        int qy = min(max((int)(kpp[1] * 2.0f), 0), GY - 1);
        int qz = min(max((int)(kpp[2] * 2.0f), 0), GZ - 1);
        s_idx[w][kk] = grid[((b * GX + qx) * GY + qy) * GZ + qz];
        float4 vi = make_float4((float)b, (float)qx, (float)qy, (float)qz);
        *(float4*)(out_vi + ((size_t)row * 8 + kk) * 4) = vi;
    }
    __syncthreads();

    float acc = 0.f;
    #pragma unroll
    for (int kk = 0; kk < 8; ++kk) {
        int gi = s_idx[w][kk];
        gi = gi < 0 ? 0 : gi;
        float v = bf2f(conv2[(size_t)gi * 64 + lane]);
        acc += fmaxf(v * sc + sh, 0.f);      // fused BN2 + ReLU
    }
    float mean = acc * 0.125f + query[(size_t)row * 64 + lane];
    s_mean[w][lane] = mean;
    __syncthreads();

    float f = projB[lane];
    const float* pwr = s_pw + lane * 65;
    const float* mv = s_mean[w];
    #pragma unroll 8
    for (int c = 0; c < 64; ++c) f += mv[c] * pwr[c];
    out_fused[(size_t)row * 64 + lane] = f;
}

// ---------------- launch ----------------
extern "C" void kernel_launch(void* const* d_in, const int* in_sizes, int n_in,
                              void* d_out, int out_size, void* d_ws, size_t ws_size,
                              hipStream_t stream) {
    const float* keypoints = (const float*)d_in[0];
    const float* query     = (const float*)d_in[1];
    const float* vfeat     = (const float*)d_in[2];
    const int*   vcoords   = (const int*)d_in[3];
    const float* W1        = (const float*)d_in[4];
    const float* g1        = (const float*)d_in[5];
    const float* b1        = (const float*)d_in[6];
    const float* W2        = (const float*)d_in[7];
    const float* g2        = (const float*)d_in[8];
    const float* b2        = (const float*)d_in[9];
    const float* pW        = (const float*)d_in[10];
    const float* pb        = (const float*)d_in[11];

    char* ws = (char*)d_ws;
    int*            grid   = (int*)ws;                          // 2,097,152 B
    float*          stats  = (float*)(ws + 2097152);            // 2048 B
    unsigned short* Wt1    = (unsigned short*)(ws + 2099200);   // 221,184 B
    unsigned short* Wt2    = (unsigned short*)(ws + 2320384);   // 221,184 B
    unsigned short* featA  = (unsigned short*)(ws + 2541568);   // 25,600,000 B
    unsigned short* featB  = (unsigned short*)(ws + 28141568);  // 25,600,000 B
    unsigned short* convo  = (unsigned short*)(ws + 53741568);  // 25,600,000 B

    float* sum1 = stats,       *sq1 = stats + 64,  *coef1 = stats + 128;
    float* sum2 = stats + 256, *sq2 = stats + 320, *coef2 = stats + 384;

    int initN = NB * CELLS + 512;
    k_init<<<(initN + 255) / 256, 256, 0, stream>>>(grid, stats);
    k_scatter<<<(NM + 255) / 256, 256, 0, stream>>>(vcoords, grid);
    k_wprep<<<(27 * 64 * 64 + 255) / 256, 256, 0, stream>>>(W1, W2, Wt1, Wt2);
    k_tobf16<<<(NM * 16 + 255) / 256, 256, 0, stream>>>(vfeat, featA, NM * 16);

    k_conv<<<(NM + TM - 1) / TM, 256, 0, stream>>>(featA, vcoords, grid, Wt1, convo, sum1, sq1);
    k_bncoef<<<1, 64, 0, stream>>>(sum1, sq1, g1, b1, coef1);
    k_bnapply<<<(NM * 8 + 255) / 256, 256, 0, stream>>>(convo, coef1, featB);

    k_conv<<<(NM + TM - 1) / TM, 256, 0, stream>>>(featB, vcoords, grid, Wt2, convo, sum2, sq2);
    k_bncoef<<<1, 64, 0, stream>>>(sum2, sq2, g2, b2, coef2);

    float* out_fused = (float*)d_out;
    float* out_vi = out_fused + (size_t)NB * NN * NC;  // 1,048,576 floats
    k_sample<<<(NB * NN) / 4, 256, 0, stream>>>(keypoints, query, convo, coef2, grid, pW, pb,
                                                out_fused, out_vi);
}